// Round 7
// baseline (2738.522 us; speedup 1.0000x reference)
//
#include <hip/hip_runtime.h>
#include <hip/hip_cooperative_groups.h>

namespace cg = cooperative_groups;

typedef _Float16 half2_t __attribute__((ext_vector_type(2)));
typedef unsigned int uint;

#define D 128
#define O 64
#define UNR 8
#define NODES_PW 25       // nodes owned per wave (coop path)
#define COOP_BLOCKS 1024  // x 4 waves x 25 nodes = 102400 >= N

static inline size_t align_up(size_t x, size_t a) { return (x + a - 1) & ~(a - 1); }

// ---------------- setup kernels ----------------

__global__ void init_deg_k(int* __restrict__ deg, int n) {
  int i = blockIdx.x * blockDim.x + threadIdx.x;
  if (i < n) deg[i] = 1;  // self loop
}

__global__ void count_deg_k(const int* __restrict__ col, int* __restrict__ deg, int E, int n) {
  int i = blockIdx.x * blockDim.x + threadIdx.x;
  if (i >= E) return;
  int c = col[i];
  if ((unsigned)c >= (unsigned)n) return;
  atomicAdd(&deg[c], 1);
}

// scan1 + dinv fused
__global__ void scan1_k(const int* __restrict__ deg, int* __restrict__ row_ptr,
                        int* __restrict__ bsum, float* __restrict__ dinv, int n) {
  __shared__ int s[256];
  int tid = threadIdx.x;
  int gid = blockIdx.x * 256 + tid;
  int dg = (gid < n) ? deg[gid] : 1;
  if (gid < n) dinv[gid] = rsqrtf((float)dg);
  int v = (gid < n) ? (dg - 1) : 0;
  s[tid] = v;
  __syncthreads();
  for (int off = 1; off < 256; off <<= 1) {
    int t = (tid >= off) ? s[tid - off] : 0;
    __syncthreads();
    s[tid] += t;
    __syncthreads();
  }
  if (gid < n) row_ptr[gid] = s[tid] - v;
  if (tid == 255) bsum[blockIdx.x] = s[255];
}

__global__ void scan2_k(int* __restrict__ bsum, int nb) {
  __shared__ int s[512];
  int tid = threadIdx.x;
  int v = (tid < nb) ? bsum[tid] : 0;
  s[tid] = v;
  __syncthreads();
  for (int off = 1; off < 512; off <<= 1) {
    int t = (tid >= off) ? s[tid - off] : 0;
    __syncthreads();
    s[tid] += t;
    __syncthreads();
  }
  if (tid < nb) bsum[tid] = s[tid] - v;
}

__global__ void scan3_k(const int* __restrict__ bsum, const int* __restrict__ deg,
                        int* __restrict__ row_ptr, int* __restrict__ cursor, int n) {
  int gid = blockIdx.x * 256 + threadIdx.x;
  if (gid < n) {
    int r = row_ptr[gid] + bsum[blockIdx.x];
    row_ptr[gid] = r;
    cursor[gid] = r;
    if (gid == n - 1) row_ptr[n] = r + deg[gid] - 1;
  }
}

// CSR fill: interleaved {src, norm} -> single 8B scatter per edge
__global__ void fill_k(const int* __restrict__ rows, const int* __restrict__ cols,
                       int* __restrict__ cursor, const float* __restrict__ dinv,
                       int2* __restrict__ csr, int E, int n) {
  int i = blockIdx.x * blockDim.x + threadIdx.x;
  if (i >= E) return;
  int u = rows[i], v = cols[i];
  if ((unsigned)v >= (unsigned)n) return;
  if ((unsigned)u >= (unsigned)n) u = 0;
  int slot = atomicAdd(&cursor[v], 1);
  float nrm = dinv[u] * dinv[v];
  csr[slot] = make_int2(u, __float_as_int(nrm));
}

// softmax over hop weights + pack W to f16x2
__global__ void prep_k(const float* __restrict__ t, float* __restrict__ tn,
                       const float* __restrict__ W, uint* __restrict__ Wpk, int step) {
  int tid = threadIdx.x;
  if (tid < D) {
    float vals[16];
    float m = -1e30f;
    for (int k = 0; k < step; ++k) { vals[k] = t[k * D + tid]; m = fmaxf(m, vals[k]); }
    float ssum = 0.f;
    for (int k = 0; k < step; ++k) { vals[k] = expf(vals[k] - m); ssum += vals[k]; }
    float inv = 1.f / ssum;
    for (int k = 0; k < step; ++k) tn[k * D + tid] = vals[k] * inv;
  }
  for (int i = tid; i < O * 64; i += 256) {
    int o = i >> 6, dd = i & 63;
    half2_t h;
    h.x = (_Float16)W[o * D + 2 * dd];
    h.y = (_Float16)W[o * D + 2 * dd + 1];
    Wpk[i] = *(uint*)&h;
  }
}

__global__ void init_h_k(const float* __restrict__ x, half2_t* __restrict__ h0, int total) {
  int i = blockIdx.x * blockDim.x + threadIdx.x;
  if (i >= total) return;
  float2 v = ((const float2*)x)[i];
  half2_t o;
  o.x = (_Float16)v.x;
  o.y = (_Float16)v.y;
  h0[i] = o;
}

__device__ __forceinline__ uint pack_f16(float a, float b) {
  half2_t h;
  h.x = (_Float16)a;
  h.y = (_Float16)b;
  return *(uint*)&h;
}

// ---------------- coop path: init + all hops in one launch ----------------
__global__ __launch_bounds__(256, 4) void hops_coop_k(
    const float* __restrict__ x, half2_t* __restrict__ h_a, half2_t* __restrict__ h_b,
    uint* __restrict__ ybuf, const int* __restrict__ row_ptr, const int2* __restrict__ csr,
    const float* __restrict__ dinv, const float* __restrict__ tn, int n, int step) {
  cg::grid_group grid = cg::this_grid();
  int wave = (blockIdx.x * blockDim.x + threadIdx.x) >> 6;
  int lane = threadIdx.x & 63;
  int v0 = __builtin_amdgcn_readfirstlane(wave * NODES_PW);

  uint hreg[NODES_PW];  // self h, packed f16x2
  uint yreg[NODES_PW];  // y accumulator, packed f16x2

  {
    float2 t0 = ((const float2*)tn)[lane];
#pragma unroll
    for (int m = 0; m < NODES_PW; ++m) {
      int vm = v0 + m;
      int vmc = vm < n ? vm : n - 1;
      float2 xv = ((const float2*)x)[(size_t)vmc * 64 + lane];
      hreg[m] = pack_f16(xv.x, xv.y);
      yreg[m] = pack_f16(t0.x * xv.x, t0.y * xv.y);
      if (vm < n) h_a[(size_t)vm * 64 + lane] = *(half2_t*)&hreg[m];
    }
  }

  for (int k = 1; k < step; ++k) {
    __threadfence();
    grid.sync();
    const half2_t* hc = (k & 1) ? h_a : h_b;
    half2_t* hw = (k & 1) ? h_b : h_a;
    float2 tk = ((const float2*)(tn + (size_t)k * D))[lane];
#pragma unroll
    for (int m = 0; m < NODES_PW; ++m) {
      int vm = v0 + m;
      int vmc = vm < n ? vm : n - 1;
      int beg = __builtin_amdgcn_readfirstlane(row_ptr[vmc]);
      int end = __builtin_amdgcn_readfirstlane(row_ptr[vmc + 1]);
      float dv = dinv[vmc];
      float ns = dv * dv;
      half2_t hv = *(half2_t*)&hreg[m];
      float ax = ns * (float)hv.x;
      float ay = ns * (float)hv.y;
      for (int i = beg; i < end; i += UNR) {
        int u[UNR];
        float w[UNR];
#pragma unroll
        for (int j = 0; j < UNR; ++j) {
          int ic = i + j;
          int icl = ic < end - 1 ? ic : end - 1;
          int2 e = csr[icl];
          u[j] = e.x;
          w[j] = (ic < end) ? __int_as_float(e.y) : 0.f;
        }
        half2_t g[UNR];
#pragma unroll
        for (int j = 0; j < UNR; ++j) g[j] = hc[(size_t)u[j] * 64 + lane];
#pragma unroll
        for (int j = 0; j < UNR; ++j) {
          ax += w[j] * (float)g[j].x;
          ay += w[j] * (float)g[j].y;
        }
      }
      hreg[m] = pack_f16(ax, ay);
      if (vm < n) hw[(size_t)vm * 64 + lane] = *(half2_t*)&hreg[m];
      half2_t yo = *(half2_t*)&yreg[m];
      yreg[m] = pack_f16((float)yo.x + tk.x * ax, (float)yo.y + tk.y * ay);
    }
  }

#pragma unroll
  for (int m = 0; m < NODES_PW; ++m) {
    int vm = v0 + m;
    if (vm < n) ybuf[(size_t)vm * 64 + lane] = yreg[m];
  }
}

// ---------------- fallback path: per-hop kernel (R4 structure, int2 CSR) ----
// DO_Y: 0 = none; 1 = y = tp*h_old + tc*h_new; 2 = y += tp*h_old + tc*h_new
template <int DO_Y>
__global__ __launch_bounds__(256) void hop_f_k(
    const half2_t* __restrict__ h_old, half2_t* __restrict__ h_new, uint* __restrict__ y,
    const int* __restrict__ row_ptr, const int2* __restrict__ csr,
    const float* __restrict__ dinv, const float* __restrict__ tprev,
    const float* __restrict__ tcur, int n) {
  int wid = (blockIdx.x * blockDim.x + threadIdx.x) >> 6;
  int lane = threadIdx.x & 63;
  if (wid >= n) return;
  int v = __builtin_amdgcn_readfirstlane(wid);
  float dv = dinv[v];
  float ns = dv * dv;
  half2_t hv = h_old[(size_t)v * 64 + lane];
  float hx = (float)hv.x, hy = (float)hv.y;
  float ax = ns * hx, ay = ns * hy;
  int beg = __builtin_amdgcn_readfirstlane(row_ptr[v]);
  int end = __builtin_amdgcn_readfirstlane(row_ptr[v + 1]);
  for (int i = beg; i < end; i += UNR) {
    int u[UNR];
    float w[UNR];
#pragma unroll
    for (int j = 0; j < UNR; ++j) {
      int ic = i + j;
      int icl = (ic < end - 1) ? ic : (end - 1);
      int2 e = csr[icl];
      u[j] = e.x;
      w[j] = (ic < end) ? __int_as_float(e.y) : 0.f;
    }
    half2_t g[UNR];
#pragma unroll
    for (int j = 0; j < UNR; ++j) g[j] = h_old[(size_t)u[j] * 64 + lane];
#pragma unroll
    for (int j = 0; j < UNR; ++j) {
      ax += w[j] * (float)g[j].x;
      ay += w[j] * (float)g[j].y;
    }
  }
  h_new[(size_t)v * 64 + lane] = *(half2_t*)&(uint&)*(uint[]){pack_f16(ax, ay)};
  if (DO_Y) {
    float2 ta = ((const float2*)tprev)[lane];
    float2 tb = ((const float2*)tcur)[lane];
    float yx = ta.x * hx + tb.x * ax;
    float yy = ta.y * hy + tb.y * ay;
    if (DO_Y == 2) {
      uint yo = y[(size_t)v * 64 + lane];
      half2_t yh = *(half2_t*)&yo;
      yx += (float)yh.x;
      yy += (float)yh.y;
    }
    y[(size_t)v * 64 + lane] = pack_f16(yx, yy);
  }
}

// ---------------- final projection: out = y @ W^T + b ----------------

__global__ __launch_bounds__(256) void proj_k(
    const uint* __restrict__ y, const uint* __restrict__ Wpk,
    const float* __restrict__ b, float* __restrict__ out, int n, int nwaves) {
  int lane = threadIdx.x & 63;
  int wid = (blockIdx.x * blockDim.x + threadIdx.x) >> 6;
  uint wreg[64];
  const uint* wp = Wpk + lane * 64;
#pragma unroll
  for (int j = 0; j < 64; ++j) wreg[j] = wp[j];
  float bias = b[lane];
  for (int v = wid; v < n; v += nwaves) {
    int vu = __builtin_amdgcn_readfirstlane(v);
    const uint* yrow = y + (size_t)vu * 64;
    float acc = bias;
#pragma unroll
    for (int dd = 0; dd < 64; ++dd) {
      uint yv = yrow[dd];
#if defined(__has_builtin) && __has_builtin(__builtin_amdgcn_fdot2)
      acc = __builtin_amdgcn_fdot2(*(half2_t*)&yv, *(half2_t*)&wreg[dd], acc, false);
#else
      half2_t yh = *(half2_t*)&yv, wh = *(half2_t*)&wreg[dd];
      acc += (float)yh.x * (float)wh.x + (float)yh.y * (float)wh.y;
#endif
    }
    out[(size_t)vu * O + lane] = acc;
  }
}

// ---------------- launch ----------------

extern "C" void kernel_launch(void* const* d_in, const int* in_sizes, int n_in,
                              void* d_out, int out_size, void* d_ws, size_t ws_size,
                              hipStream_t stream) {
  const float* x = (const float*)d_in[0];
  const int* ei = (const int*)d_in[1];
  const float* t = (const float*)d_in[2];
  const float* W = (const float*)d_in[3];
  const float* b = (const float*)d_in[4];
  float* out = (float*)d_out;

  int n = in_sizes[0] / D;
  int E = in_sizes[1] / 2;
  int step = in_sizes[2] / D;  // = 10
  const int* rows = ei;
  const int* cols = ei + E;

  char* p = (char*)d_ws;
  auto alloc = [&](size_t bytes) { char* r = p; p += align_up(bytes, 256); return r; };
  int*     deg      = (int*)alloc((size_t)n * 4);
  float*   dinv     = (float*)alloc((size_t)n * 4);
  int*     row_ptr  = (int*)alloc((size_t)(n + 1) * 4);
  int*     cursor   = (int*)alloc((size_t)n * 4);
  int*     bsum     = (int*)alloc(2048);
  int2*    csr      = (int2*)alloc((size_t)E * 8);
  float*   tn       = (float*)alloc((size_t)step * D * 4);
  uint*    Wpk      = (uint*)alloc((size_t)O * 64 * 4);
  half2_t* h_a      = (half2_t*)alloc((size_t)n * 64 * 4);
  half2_t* h_b      = (half2_t*)alloc((size_t)n * 64 * 4);
  uint*    ybuf     = (uint*)alloc((size_t)n * 64 * 4);

  int nb1 = (n + 255) / 256;
  init_deg_k<<<nb1, 256, 0, stream>>>(deg, n);
  count_deg_k<<<(E + 255) / 256, 256, 0, stream>>>(cols, deg, E, n);
  scan1_k<<<nb1, 256, 0, stream>>>(deg, row_ptr, bsum, dinv, n);
  scan2_k<<<1, 512, 0, stream>>>(bsum, nb1);
  scan3_k<<<nb1, 256, 0, stream>>>(bsum, deg, row_ptr, cursor, n);
  fill_k<<<(E + 255) / 256, 256, 0, stream>>>(rows, cols, cursor, dinv, csr, E, n);
  prep_k<<<1, 256, 0, stream>>>(t, tn, W, Wpk, step);

  // try cooperative single-launch path; verified fall back on ANY error
  half2_t* ha = h_a;
  half2_t* hb = h_b;
  void* args[] = {(void*)&x, (void*)&ha, (void*)&hb, (void*)&ybuf, (void*)&row_ptr,
                  (void*)&csr, (void*)&dinv, (void*)&tn, (void*)&n, (void*)&step};
  hipError_t ce = hipLaunchCooperativeKernel((const void*)hops_coop_k, dim3(COOP_BLOCKS),
                                             dim3(256), args, 0, stream);
  if (ce != hipSuccess) {
    // fallback: per-hop launches (implicit inter-launch sync)
    init_h_k<<<((size_t)n * 64 + 255) / 256, 256, 0, stream>>>(x, h_a, n * 64);
    half2_t* ho = h_a;
    half2_t* hn = h_b;
    int hop_blocks = (n + 3) / 4;
    for (int k = 1; k < step; ++k) {
      const float* tp = tn + (size_t)(k - 1) * D;
      const float* tc = tn + (size_t)k * D;
      if (k & 1) {
        if (k == 1)
          hop_f_k<1><<<hop_blocks, 256, 0, stream>>>(ho, hn, ybuf, row_ptr, csr, dinv, tp, tc, n);
        else
          hop_f_k<2><<<hop_blocks, 256, 0, stream>>>(ho, hn, ybuf, row_ptr, csr, dinv, tp, tc, n);
      } else {
        hop_f_k<0><<<hop_blocks, 256, 0, stream>>>(ho, hn, ybuf, row_ptr, csr, dinv, tp, tc, n);
      }
      half2_t* tmp = ho; ho = hn; hn = tmp;
    }
  }

  int proj_blocks = 512;
  int nwaves = proj_blocks * 4;
  proj_k<<<proj_blocks, 256, 0, stream>>>(ybuf, Wpk, b, out, n, nwaves);
}

// Round 8
// 543.052 us; speedup vs baseline: 5.0428x; 5.0428x over previous
//
#include <hip/hip_runtime.h>

typedef _Float16 half2_t __attribute__((ext_vector_type(2)));
typedef unsigned int uint;

#define D 128
#define O 64
#define UNR 8

static inline size_t align_up(size_t x, size_t a) { return (x + a - 1) & ~(a - 1); }

__device__ __forceinline__ uint pack_f16(float a, float b) {
  half2_t h;
  h.x = (_Float16)a;
  h.y = (_Float16)b;
  return *(uint*)&h;
}

__device__ __forceinline__ float dot2f(uint a, uint b, float c) {
#if defined(__has_builtin) && __has_builtin(__builtin_amdgcn_fdot2)
  return __builtin_amdgcn_fdot2(*(half2_t*)&a, *(half2_t*)&b, c, false);
#else
  half2_t ha = *(half2_t*)&a, hb = *(half2_t*)&b;
  return c + (float)ha.x * (float)hb.x + (float)ha.y * (float)hb.y;
#endif
}

// ---------------- setup kernels ----------------
// deg = in-edge count (no self loop; memset to 0 before). dinv = rsqrt(deg+1).

__global__ void count_deg_k(const int* __restrict__ col, int* __restrict__ deg, int E, int n) {
  int i = blockIdx.x * blockDim.x + threadIdx.x;
  if (i >= E) return;
  int c = col[i];
  if ((unsigned)c >= (unsigned)n) return;
  atomicAdd(&deg[c], 1);
}

__global__ void scan1_k(const int* __restrict__ deg, int* __restrict__ row_ptr,
                        int* __restrict__ bsum, float* __restrict__ dinv, int n) {
  __shared__ int s[256];
  int tid = threadIdx.x;
  int gid = blockIdx.x * 256 + tid;
  int dg = (gid < n) ? deg[gid] : 0;
  if (gid < n) dinv[gid] = rsqrtf((float)(dg + 1));
  s[tid] = dg;
  __syncthreads();
  for (int off = 1; off < 256; off <<= 1) {
    int t = (tid >= off) ? s[tid - off] : 0;
    __syncthreads();
    s[tid] += t;
    __syncthreads();
  }
  if (gid < n) row_ptr[gid] = s[tid] - dg;  // block-local exclusive
  if (tid == 255) bsum[blockIdx.x] = s[255];
}

__global__ void scan2_k(int* __restrict__ bsum, int nb) {
  __shared__ int s[512];
  int tid = threadIdx.x;
  int v = (tid < nb) ? bsum[tid] : 0;
  s[tid] = v;
  __syncthreads();
  for (int off = 1; off < 512; off <<= 1) {
    int t = (tid >= off) ? s[tid - off] : 0;
    __syncthreads();
    s[tid] += t;
    __syncthreads();
  }
  if (tid < nb) bsum[tid] = s[tid] - v;
}

__global__ void scan3_k(const int* __restrict__ bsum, const int* __restrict__ deg,
                        int* __restrict__ row_ptr, int* __restrict__ cursor, int n) {
  int gid = blockIdx.x * 256 + threadIdx.x;
  if (gid < n) {
    int r = row_ptr[gid] + bsum[blockIdx.x];
    row_ptr[gid] = r;
    cursor[gid] = r;
    if (gid == n - 1) row_ptr[n] = r + deg[gid];
  }
}

__global__ void fill_k(const int* __restrict__ rows, const int* __restrict__ cols,
                       int* __restrict__ cursor, const float* __restrict__ dinv,
                       int2* __restrict__ csr, int E, int n) {
  int i = blockIdx.x * blockDim.x + threadIdx.x;
  if (i >= E) return;
  int u = rows[i], v = cols[i];
  if ((unsigned)v >= (unsigned)n) return;  // must match count_deg_k skip
  if ((unsigned)u >= (unsigned)n) u = 0;
  int slot = atomicAdd(&cursor[v], 1);
  float nrm = dinv[u] * dinv[v];
  csr[slot] = make_int2(u, __float_as_int(nrm));
}

// softmax over hop weights + pack W rows to f16x2
__global__ void prep_k(const float* __restrict__ t, float* __restrict__ tn,
                       const float* __restrict__ W, uint* __restrict__ Wpk, int step) {
  int tid = threadIdx.x;
  if (tid < D) {
    float vals[16];
    float m = -1e30f;
    for (int k = 0; k < step; ++k) { vals[k] = t[k * D + tid]; m = fmaxf(m, vals[k]); }
    float ssum = 0.f;
    for (int k = 0; k < step; ++k) { vals[k] = expf(vals[k] - m); ssum += vals[k]; }
    float inv = 1.f / ssum;
    for (int k = 0; k < step; ++k) tn[k * D + tid] = vals[k] * inv;
  }
  for (int i = tid; i < O * 64; i += 256) {
    int o = i >> 6, dd = i & 63;
    Wpk[i] = pack_f16(W[o * D + 2 * dd], W[o * D + 2 * dd + 1]);
  }
}

// ---------------- hop: pure SpMM h_dst = A_norm * h_src ----------------
// One wave per node; 8-wide pipelined gathers; SRC32 => gather fp32 (x).

template <bool SRC32>
__global__ __launch_bounds__(256) void hop_k(
    const void* __restrict__ hsrc, uint* __restrict__ hdst,
    const int* __restrict__ row_ptr, const int2* __restrict__ csr,
    const float* __restrict__ dinv, int n) {
  int wid = (blockIdx.x * blockDim.x + threadIdx.x) >> 6;
  int lane = threadIdx.x & 63;
  if (wid >= n) return;
  int v = __builtin_amdgcn_readfirstlane(wid);
  const float2* s32 = (const float2*)hsrc;
  const uint* s16 = (const uint*)hsrc;
  float dv = dinv[v];
  float ns = dv * dv;  // self-loop norm
  float hx, hy;
  if (SRC32) {
    float2 hv = s32[(size_t)v * 64 + lane];
    hx = hv.x; hy = hv.y;
  } else {
    uint hp = s16[(size_t)v * 64 + lane];
    half2_t hv = *(half2_t*)&hp;
    hx = (float)hv.x; hy = (float)hv.y;
  }
  float ax = ns * hx, ay = ns * hy;
  int beg = __builtin_amdgcn_readfirstlane(row_ptr[v]);
  int end = __builtin_amdgcn_readfirstlane(row_ptr[v + 1]);
  for (int i = beg; i < end; i += UNR) {
    int u[UNR];
    float w[UNR];
#pragma unroll
    for (int j = 0; j < UNR; ++j) {
      int ic = i + j;
      int icl = (ic < end - 1) ? ic : (end - 1);
      int2 e = csr[icl];
      u[j] = e.x;
      w[j] = (ic < end) ? __int_as_float(e.y) : 0.f;
    }
    float gx[UNR], gy[UNR];
    if (SRC32) {
      float2 g[UNR];
#pragma unroll
      for (int j = 0; j < UNR; ++j) g[j] = s32[(size_t)u[j] * 64 + lane];
#pragma unroll
      for (int j = 0; j < UNR; ++j) { gx[j] = g[j].x; gy[j] = g[j].y; }
    } else {
      uint g[UNR];
#pragma unroll
      for (int j = 0; j < UNR; ++j) g[j] = s16[(size_t)u[j] * 64 + lane];
#pragma unroll
      for (int j = 0; j < UNR; ++j) {
        half2_t h = *(half2_t*)&g[j];
        gx[j] = (float)h.x; gy[j] = (float)h.y;
      }
    }
#pragma unroll
    for (int j = 0; j < UNR; ++j) {
      ax += w[j] * gx[j];
      ay += w[j] * gy[j];
    }
  }
  hdst[(size_t)v * 64 + lane] = pack_f16(ax, ay);
}

// ---------------- proj: y = sum_k tn[k]*h_k ; out = y @ W^T + b ----------------
// Per node: build y (fp32) from streams, broadcast via LDS (f16x2), 64 dot2.

template <int STEPT>
__global__ __launch_bounds__(256) void proj_k(
    const float* __restrict__ x, const uint* __restrict__ hbuf, size_t hstride,
    const uint* __restrict__ Wpk, const float* __restrict__ tn,
    const float* __restrict__ b, float* __restrict__ out, int n, int nwaves, int step) {
  __shared__ uint sy[4][64];
  int tid = threadIdx.x;
  int lane = tid & 63, wv = tid >> 6;
  uint wreg[64];
  const uint* wp = Wpk + lane * 64;
#pragma unroll
  for (int j = 0; j < 64; ++j) wreg[j] = wp[j];
  float bias = b[lane];
  float2 tt[STEPT > 0 ? STEPT : 1];
  if (STEPT > 0) {
#pragma unroll
    for (int k = 0; k < STEPT; ++k) tt[k] = ((const float2*)(tn + (size_t)k * D))[lane];
  }
  int wid = (blockIdx.x * blockDim.x + tid) >> 6;
  for (int v = wid; v < n; v += nwaves) {
    float2 xv = ((const float2*)x)[(size_t)v * 64 + lane];
    float yx, yy;
    if (STEPT > 0) {
      yx = tt[0].x * xv.x;
      yy = tt[0].y * xv.y;
#pragma unroll
      for (int k = 1; k < STEPT; ++k) {
        uint hp = hbuf[(size_t)(k - 1) * hstride + (size_t)v * 64 + lane];
        half2_t h = *(half2_t*)&hp;
        yx += tt[k].x * (float)h.x;
        yy += tt[k].y * (float)h.y;
      }
    } else {
      float2 t0 = ((const float2*)tn)[lane];
      yx = t0.x * xv.x;
      yy = t0.y * xv.y;
      for (int k = 1; k < step; ++k) {
        uint hp = hbuf[(size_t)(k - 1) * hstride + (size_t)v * 64 + lane];
        half2_t h = *(half2_t*)&hp;
        float2 tk = ((const float2*)(tn + (size_t)k * D))[lane];
        yx += tk.x * (float)h.x;
        yy += tk.y * (float)h.y;
      }
    }
    sy[wv][lane] = pack_f16(yx, yy);  // wave-local broadcast buffer (in-order LDS)
    float acc = bias;
#pragma unroll
    for (int q = 0; q < 16; ++q) {
      uint4 yq = *(const uint4*)&sy[wv][q * 4];  // broadcast b128 read
      acc = dot2f(yq.x, wreg[q * 4 + 0], acc);
      acc = dot2f(yq.y, wreg[q * 4 + 1], acc);
      acc = dot2f(yq.z, wreg[q * 4 + 2], acc);
      acc = dot2f(yq.w, wreg[q * 4 + 3], acc);
    }
    out[(size_t)v * O + lane] = acc;
  }
}

// ---------------- fallback path (ws too small): R4-proven structure ----------

__global__ void init_h_k(const float* __restrict__ x, uint* __restrict__ h0, int total) {
  int i = blockIdx.x * blockDim.x + threadIdx.x;
  if (i >= total) return;
  float2 v = ((const float2*)x)[i];
  h0[i] = pack_f16(v.x, v.y);
}

template <int DO_Y>
__global__ __launch_bounds__(256) void hop_f_k(
    const uint* __restrict__ h_old, uint* __restrict__ h_new, uint* __restrict__ y,
    const int* __restrict__ row_ptr, const int2* __restrict__ csr,
    const float* __restrict__ dinv, const float* __restrict__ tprev,
    const float* __restrict__ tcur, int n) {
  int wid = (blockIdx.x * blockDim.x + threadIdx.x) >> 6;
  int lane = threadIdx.x & 63;
  if (wid >= n) return;
  int v = __builtin_amdgcn_readfirstlane(wid);
  float dv = dinv[v];
  float ns = dv * dv;
  uint hp = h_old[(size_t)v * 64 + lane];
  half2_t hv = *(half2_t*)&hp;
  float hx = (float)hv.x, hy = (float)hv.y;
  float ax = ns * hx, ay = ns * hy;
  int beg = __builtin_amdgcn_readfirstlane(row_ptr[v]);
  int end = __builtin_amdgcn_readfirstlane(row_ptr[v + 1]);
  for (int i = beg; i < end; i += UNR) {
    int u[UNR];
    float w[UNR];
#pragma unroll
    for (int j = 0; j < UNR; ++j) {
      int ic = i + j;
      int icl = (ic < end - 1) ? ic : (end - 1);
      int2 e = csr[icl];
      u[j] = e.x;
      w[j] = (ic < end) ? __int_as_float(e.y) : 0.f;
    }
    uint g[UNR];
#pragma unroll
    for (int j = 0; j < UNR; ++j) g[j] = h_old[(size_t)u[j] * 64 + lane];
#pragma unroll
    for (int j = 0; j < UNR; ++j) {
      half2_t h = *(half2_t*)&g[j];
      ax += w[j] * (float)h.x;
      ay += w[j] * (float)h.y;
    }
  }
  h_new[(size_t)v * 64 + lane] = pack_f16(ax, ay);
  if (DO_Y) {
    float2 ta = ((const float2*)tprev)[lane];
    float2 tb = ((const float2*)tcur)[lane];
    float yx = ta.x * hx + tb.x * ax;
    float yy = ta.y * hy + tb.y * ay;
    if (DO_Y == 2) {
      uint yo = y[(size_t)v * 64 + lane];
      half2_t yh = *(half2_t*)&yo;
      yx += (float)yh.x;
      yy += (float)yh.y;
    }
    y[(size_t)v * 64 + lane] = pack_f16(yx, yy);
  }
}

__global__ __launch_bounds__(256) void proj_y_k(
    const uint* __restrict__ y, const uint* __restrict__ Wpk,
    const float* __restrict__ b, float* __restrict__ out, int n, int nwaves) {
  int lane = threadIdx.x & 63;
  int wid = (blockIdx.x * blockDim.x + threadIdx.x) >> 6;
  uint wreg[64];
  const uint* wp = Wpk + lane * 64;
#pragma unroll
  for (int j = 0; j < 64; ++j) wreg[j] = wp[j];
  float bias = b[lane];
  for (int v = wid; v < n; v += nwaves) {
    int vu = __builtin_amdgcn_readfirstlane(v);
    const uint* yrow = y + (size_t)vu * 64;
    float acc = bias;
#pragma unroll
    for (int dd = 0; dd < 64; ++dd) acc = dot2f(yrow[dd], wreg[dd], acc);
    out[(size_t)vu * O + lane] = acc;
  }
}

// ---------------- launch ----------------

extern "C" void kernel_launch(void* const* d_in, const int* in_sizes, int n_in,
                              void* d_out, int out_size, void* d_ws, size_t ws_size,
                              hipStream_t stream) {
  const float* x = (const float*)d_in[0];
  const int* ei = (const int*)d_in[1];
  const float* t = (const float*)d_in[2];
  const float* W = (const float*)d_in[3];
  const float* b = (const float*)d_in[4];
  float* out = (float*)d_out;

  int n = in_sizes[0] / D;
  int E = in_sizes[1] / 2;
  int step = in_sizes[2] / D;  // = 10
  const int* rows = ei;        // sources
  const int* cols = ei + E;    // targets

  char* p = (char*)d_ws;
  auto alloc = [&](size_t bytes) { char* r = p; p += align_up(bytes, 256); return r; };
  int*   deg     = (int*)alloc((size_t)n * 4);
  float* dinv    = (float*)alloc((size_t)n * 4);
  int*   row_ptr = (int*)alloc((size_t)(n + 1) * 4);
  int*   cursor  = (int*)alloc((size_t)n * 4);
  int*   bsum    = (int*)alloc(2048);
  int2*  csr     = (int2*)alloc((size_t)E * 8);
  float* tn      = (float*)alloc((size_t)step * D * 4);
  uint*  Wpk     = (uint*)alloc((size_t)O * 64 * 4);

  size_t NS = (size_t)n * 64;  // uints per h buffer
  size_t base = (size_t)(p - (char*)d_ws);
  size_t full_need = base + (size_t)(step - 1) * NS * 4;
  bool full = (ws_size >= full_need) && (step >= 2);

  // ---- common setup ----
  hipMemsetAsync(deg, 0, (size_t)n * 4, stream);
  int nb1 = (n + 255) / 256;
  count_deg_k<<<(E + 255) / 256, 256, 0, stream>>>(cols, deg, E, n);
  scan1_k<<<nb1, 256, 0, stream>>>(deg, row_ptr, bsum, dinv, n);
  scan2_k<<<1, 512, 0, stream>>>(bsum, nb1);
  scan3_k<<<nb1, 256, 0, stream>>>(bsum, deg, row_ptr, cursor, n);
  fill_k<<<(E + 255) / 256, 256, 0, stream>>>(rows, cols, cursor, dinv, csr, E, n);
  prep_k<<<1, 256, 0, stream>>>(t, tn, W, Wpk, step);

  int hop_blocks = (n + 3) / 4;  // 1 node/wave, 4 waves/block
  int proj_blocks = 512;
  int nwaves = proj_blocks * 4;

  if (full) {
    uint* hbuf = (uint*)alloc((size_t)(step - 1) * NS * 4);
    // hop 1: gather straight from fp32 x
    hop_k<true><<<hop_blocks, 256, 0, stream>>>(x, hbuf, row_ptr, csr, dinv, n);
    for (int k = 2; k < step; ++k) {
      hop_k<false><<<hop_blocks, 256, 0, stream>>>(hbuf + (size_t)(k - 2) * NS,
                                                   hbuf + (size_t)(k - 1) * NS,
                                                   row_ptr, csr, dinv, n);
    }
    if (step == 10)
      proj_k<10><<<proj_blocks, 256, 0, stream>>>(x, hbuf, NS, Wpk, tn, b, out, n, nwaves, step);
    else
      proj_k<0><<<proj_blocks, 256, 0, stream>>>(x, hbuf, NS, Wpk, tn, b, out, n, nwaves, step);
  } else {
    // fallback: R4-proven ping-pong with fused y (needs 3 buffers)
    uint* h_a  = (uint*)alloc(NS * 4);
    uint* h_b  = (uint*)alloc(NS * 4);
    uint* ybuf = (uint*)alloc(NS * 4);
    init_h_k<<<((size_t)NS + 255) / 256, 256, 0, stream>>>(x, h_a, (int)NS);
    uint* ho = h_a;
    uint* hn = h_b;
    for (int k = 1; k < step; ++k) {
      const float* tp = tn + (size_t)(k - 1) * D;
      const float* tc = tn + (size_t)k * D;
      if (k & 1) {
        if (k == 1)
          hop_f_k<1><<<hop_blocks, 256, 0, stream>>>(ho, hn, ybuf, row_ptr, csr, dinv, tp, tc, n);
        else
          hop_f_k<2><<<hop_blocks, 256, 0, stream>>>(ho, hn, ybuf, row_ptr, csr, dinv, tp, tc, n);
      } else {
        hop_f_k<0><<<hop_blocks, 256, 0, stream>>>(ho, hn, ybuf, row_ptr, csr, dinv, tp, tc, n);
      }
      uint* tmp = ho; ho = hn; hn = tmp;
    }
    proj_y_k<<<proj_blocks, 256, 0, stream>>>(ybuf, Wpk, b, out, n, nwaves);
  }
}

// Round 9
// 518.913 us; speedup vs baseline: 5.2774x; 1.0465x over previous
//
#include <hip/hip_runtime.h>

typedef _Float16 half2_t __attribute__((ext_vector_type(2)));
typedef unsigned int uint;

#define D 128
#define O 64
#define UNR 8

static inline size_t align_up(size_t x, size_t a) { return (x + a - 1) & ~(a - 1); }

__device__ __forceinline__ uint pack_f16(float a, float b) {
  half2_t h;
  h.x = (_Float16)a;
  h.y = (_Float16)b;
  return *(uint*)&h;
}

__device__ __forceinline__ float dot2f(uint a, uint b, float c) {
#if defined(__has_builtin) && __has_builtin(__builtin_amdgcn_fdot2)
  return __builtin_amdgcn_fdot2(*(half2_t*)&a, *(half2_t*)&b, c, false);
#else
  half2_t ha = *(half2_t*)&a, hb = *(half2_t*)&b;
  return c + (float)ha.x * (float)hb.x + (float)ha.y * (float)hb.y;
#endif
}

// ---------------- setup kernels ----------------
// deg = in-edge count (no self loop; memset to 0 before). dinv = rsqrt(deg+1).

__global__ void count_deg_k(const int* __restrict__ col, int* __restrict__ deg, int E, int n) {
  int i = blockIdx.x * blockDim.x + threadIdx.x;
  if (i >= E) return;
  int c = col[i];
  if ((unsigned)c >= (unsigned)n) return;
  atomicAdd(&deg[c], 1);
}

__global__ void scan1_k(const int* __restrict__ deg, int* __restrict__ row_ptr,
                        int* __restrict__ bsum, float* __restrict__ dinv, int n) {
  __shared__ int s[256];
  int tid = threadIdx.x;
  int gid = blockIdx.x * 256 + tid;
  int dg = (gid < n) ? deg[gid] : 0;
  if (gid < n) dinv[gid] = rsqrtf((float)(dg + 1));
  s[tid] = dg;
  __syncthreads();
  for (int off = 1; off < 256; off <<= 1) {
    int t = (tid >= off) ? s[tid - off] : 0;
    __syncthreads();
    s[tid] += t;
    __syncthreads();
  }
  if (gid < n) row_ptr[gid] = s[tid] - dg;  // block-local exclusive
  if (tid == 255) bsum[blockIdx.x] = s[255];
}

__global__ void scan2_k(int* __restrict__ bsum, int nb) {
  __shared__ int s[512];
  int tid = threadIdx.x;
  int v = (tid < nb) ? bsum[tid] : 0;
  s[tid] = v;
  __syncthreads();
  for (int off = 1; off < 512; off <<= 1) {
    int t = (tid >= off) ? s[tid - off] : 0;
    __syncthreads();
    s[tid] += t;
    __syncthreads();
  }
  if (tid < nb) bsum[tid] = s[tid] - v;
}

__global__ void scan3_k(const int* __restrict__ bsum, const int* __restrict__ deg,
                        int* __restrict__ row_ptr, int* __restrict__ cursor, int n) {
  int gid = blockIdx.x * 256 + threadIdx.x;
  if (gid < n) {
    int r = row_ptr[gid] + bsum[blockIdx.x];
    row_ptr[gid] = r;
    cursor[gid] = r;
    if (gid == n - 1) row_ptr[n] = r + deg[gid];
  }
}

__global__ void fill_k(const int* __restrict__ rows, const int* __restrict__ cols,
                       int* __restrict__ cursor, const float* __restrict__ dinv,
                       int2* __restrict__ csr, int E, int n) {
  int i = blockIdx.x * blockDim.x + threadIdx.x;
  if (i >= E) return;
  int u = rows[i], v = cols[i];
  if ((unsigned)v >= (unsigned)n) return;  // must match count_deg_k skip
  if ((unsigned)u >= (unsigned)n) u = 0;
  int slot = atomicAdd(&cursor[v], 1);
  float nrm = dinv[u] * dinv[v];
  csr[slot] = make_int2(u, __float_as_int(nrm));
}

// softmax over hop weights + pack W to f16x2, TRANSPOSED: Wpk[dd*64+o]
__global__ void prep_k(const float* __restrict__ t, float* __restrict__ tn,
                       const float* __restrict__ W, uint* __restrict__ Wpk, int step) {
  int tid = threadIdx.x;
  if (tid < D) {
    float vals[16];
    float m = -1e30f;
    for (int k = 0; k < step; ++k) { vals[k] = t[k * D + tid]; m = fmaxf(m, vals[k]); }
    float ssum = 0.f;
    for (int k = 0; k < step; ++k) { vals[k] = expf(vals[k] - m); ssum += vals[k]; }
    float inv = 1.f / ssum;
    for (int k = 0; k < step; ++k) tn[k * D + tid] = vals[k] * inv;
  }
  for (int i = tid; i < O * 64; i += 256) {
    int o = i & 63, dd = i >> 6;  // i = dd*64 + o
    Wpk[i] = pack_f16(W[o * D + 2 * dd], W[o * D + 2 * dd + 1]);
  }
}

__global__ void init_h_k(const float* __restrict__ x, uint* __restrict__ h0, int total) {
  int i = blockIdx.x * blockDim.x + threadIdx.x;
  if (i >= total) return;
  float2 v = ((const float2*)x)[i];
  h0[i] = pack_f16(v.x, v.y);
}

// ---------------- hop: pure SpMM h_dst = A_norm * h_src ----------------
// One wave per node; 8-wide pipelined 256B f16 gathers (4 lines/edge).

template <bool SRC32>
__global__ __launch_bounds__(256) void hop_k(
    const void* __restrict__ hsrc, uint* __restrict__ hdst,
    const int* __restrict__ row_ptr, const int2* __restrict__ csr,
    const float* __restrict__ dinv, int n) {
  int wid = (blockIdx.x * blockDim.x + threadIdx.x) >> 6;
  int lane = threadIdx.x & 63;
  if (wid >= n) return;
  int v = __builtin_amdgcn_readfirstlane(wid);
  const float2* s32 = (const float2*)hsrc;
  const uint* s16 = (const uint*)hsrc;
  float dv = dinv[v];
  float ns = dv * dv;  // self-loop norm
  float hx, hy;
  if (SRC32) {
    float2 hv = s32[(size_t)v * 64 + lane];
    hx = hv.x; hy = hv.y;
  } else {
    uint hp = s16[(size_t)v * 64 + lane];
    half2_t hv = *(half2_t*)&hp;
    hx = (float)hv.x; hy = (float)hv.y;
  }
  float ax = ns * hx, ay = ns * hy;
  int beg = __builtin_amdgcn_readfirstlane(row_ptr[v]);
  int end = __builtin_amdgcn_readfirstlane(row_ptr[v + 1]);
  for (int i = beg; i < end; i += UNR) {
    int u[UNR];
    float w[UNR];
#pragma unroll
    for (int j = 0; j < UNR; ++j) {
      int ic = i + j;
      int icl = (ic < end - 1) ? ic : (end - 1);
      int2 e = csr[icl];
      u[j] = e.x;
      w[j] = (ic < end) ? __int_as_float(e.y) : 0.f;
    }
    float gx[UNR], gy[UNR];
    if (SRC32) {
      float2 g[UNR];
#pragma unroll
      for (int j = 0; j < UNR; ++j) g[j] = s32[(size_t)u[j] * 64 + lane];
#pragma unroll
      for (int j = 0; j < UNR; ++j) { gx[j] = g[j].x; gy[j] = g[j].y; }
    } else {
      uint g[UNR];
#pragma unroll
      for (int j = 0; j < UNR; ++j) g[j] = s16[(size_t)u[j] * 64 + lane];
#pragma unroll
      for (int j = 0; j < UNR; ++j) {
        half2_t h = *(half2_t*)&g[j];
        gx[j] = (float)h.x; gy[j] = (float)h.y;
      }
    }
#pragma unroll
    for (int j = 0; j < UNR; ++j) {
      ax += w[j] * gx[j];
      ay += w[j] * gy[j];
    }
  }
  hdst[(size_t)v * 64 + lane] = pack_f16(ax, ay);
}

// ---------------- proj: y = sum_k tn[k]*h_k ; out = y @ W^T + b ----------------

template <int STEPT>
__global__ __launch_bounds__(256) void proj_k(
    const float* __restrict__ x, const uint* __restrict__ hbuf, size_t hstride,
    const uint* __restrict__ Wpk, const float* __restrict__ tn,
    const float* __restrict__ b, float* __restrict__ out, int n, int nwaves, int step) {
  __shared__ uint sy[4][64];
  int tid = threadIdx.x;
  int lane = tid & 63, wv = tid >> 6;
  uint wreg[64];
#pragma unroll
  for (int j = 0; j < 64; ++j) wreg[j] = Wpk[j * 64 + lane];  // coalesced (transposed)
  float bias = b[lane];
  float2 tt[STEPT > 0 ? STEPT : 1];
  if (STEPT > 0) {
#pragma unroll
    for (int k = 0; k < STEPT; ++k) tt[k] = ((const float2*)(tn + (size_t)k * D))[lane];
  }
  int wid = (blockIdx.x * blockDim.x + tid) >> 6;
  for (int v = wid; v < n; v += nwaves) {
    float2 xv = ((const float2*)x)[(size_t)v * 64 + lane];
    float yx, yy;
    if (STEPT > 0) {
      yx = tt[0].x * xv.x;
      yy = tt[0].y * xv.y;
#pragma unroll
      for (int k = 1; k < STEPT; ++k) {
        uint hp = hbuf[(size_t)(k - 1) * hstride + (size_t)v * 64 + lane];
        half2_t h = *(half2_t*)&hp;
        yx += tt[k].x * (float)h.x;
        yy += tt[k].y * (float)h.y;
      }
    } else {
      float2 t0 = ((const float2*)tn)[lane];
      yx = t0.x * xv.x;
      yy = t0.y * xv.y;
      for (int k = 1; k < step; ++k) {
        uint hp = hbuf[(size_t)(k - 1) * hstride + (size_t)v * 64 + lane];
        half2_t h = *(half2_t*)&hp;
        float2 tk = ((const float2*)(tn + (size_t)k * D))[lane];
        yx += tk.x * (float)h.x;
        yy += tk.y * (float)h.y;
      }
    }
    sy[wv][lane] = pack_f16(yx, yy);  // wave-local broadcast buffer
    float acc = bias;
#pragma unroll
    for (int q = 0; q < 16; ++q) {
      uint4 yq = *(const uint4*)&sy[wv][q * 4];  // broadcast b128 read
      acc = dot2f(yq.x, wreg[q * 4 + 0], acc);
      acc = dot2f(yq.y, wreg[q * 4 + 1], acc);
      acc = dot2f(yq.z, wreg[q * 4 + 2], acc);
      acc = dot2f(yq.w, wreg[q * 4 + 3], acc);
    }
    out[(size_t)v * O + lane] = acc;
  }
}

// ---------------- fallback path (ws too small): R4-proven structure ----------

template <int DO_Y>
__global__ __launch_bounds__(256) void hop_f_k(
    const uint* __restrict__ h_old, uint* __restrict__ h_new, uint* __restrict__ y,
    const int* __restrict__ row_ptr, const int2* __restrict__ csr,
    const float* __restrict__ dinv, const float* __restrict__ tprev,
    const float* __restrict__ tcur, int n) {
  int wid = (blockIdx.x * blockDim.x + threadIdx.x) >> 6;
  int lane = threadIdx.x & 63;
  if (wid >= n) return;
  int v = __builtin_amdgcn_readfirstlane(wid);
  float dv = dinv[v];
  float ns = dv * dv;
  uint hp = h_old[(size_t)v * 64 + lane];
  half2_t hv = *(half2_t*)&hp;
  float hx = (float)hv.x, hy = (float)hv.y;
  float ax = ns * hx, ay = ns * hy;
  int beg = __builtin_amdgcn_readfirstlane(row_ptr[v]);
  int end = __builtin_amdgcn_readfirstlane(row_ptr[v + 1]);
  for (int i = beg; i < end; i += UNR) {
    int u[UNR];
    float w[UNR];
#pragma unroll
    for (int j = 0; j < UNR; ++j) {
      int ic = i + j;
      int icl = (ic < end - 1) ? ic : (end - 1);
      int2 e = csr[icl];
      u[j] = e.x;
      w[j] = (ic < end) ? __int_as_float(e.y) : 0.f;
    }
    uint g[UNR];
#pragma unroll
    for (int j = 0; j < UNR; ++j) g[j] = h_old[(size_t)u[j] * 64 + lane];
#pragma unroll
    for (int j = 0; j < UNR; ++j) {
      half2_t h = *(half2_t*)&g[j];
      ax += w[j] * (float)h.x;
      ay += w[j] * (float)h.y;
    }
  }
  h_new[(size_t)v * 64 + lane] = pack_f16(ax, ay);
  if (DO_Y) {
    float2 ta = ((const float2*)tprev)[lane];
    float2 tb = ((const float2*)tcur)[lane];
    float yx = ta.x * hx + tb.x * ax;
    float yy = ta.y * hy + tb.y * ay;
    if (DO_Y == 2) {
      uint yo = y[(size_t)v * 64 + lane];
      half2_t yh = *(half2_t*)&yo;
      yx += (float)yh.x;
      yy += (float)yh.y;
    }
    y[(size_t)v * 64 + lane] = pack_f16(yx, yy);
  }
}

__global__ __launch_bounds__(256) void proj_y_k(
    const uint* __restrict__ y, const uint* __restrict__ Wpk,
    const float* __restrict__ b, float* __restrict__ out, int n, int nwaves) {
  int lane = threadIdx.x & 63;
  int wid = (blockIdx.x * blockDim.x + threadIdx.x) >> 6;
  uint wreg[64];
#pragma unroll
  for (int j = 0; j < 64; ++j) wreg[j] = Wpk[j * 64 + lane];  // transposed layout
  float bias = b[lane];
  for (int v = wid; v < n; v += nwaves) {
    int vu = __builtin_amdgcn_readfirstlane(v);
    const uint* yrow = y + (size_t)vu * 64;
    float acc = bias;
#pragma unroll
    for (int dd = 0; dd < 64; ++dd) acc = dot2f(yrow[dd], wreg[dd], acc);
    out[(size_t)vu * O + lane] = acc;
  }
}

// ---------------- launch ----------------

extern "C" void kernel_launch(void* const* d_in, const int* in_sizes, int n_in,
                              void* d_out, int out_size, void* d_ws, size_t ws_size,
                              hipStream_t stream) {
  const float* x = (const float*)d_in[0];
  const int* ei = (const int*)d_in[1];
  const float* t = (const float*)d_in[2];
  const float* W = (const float*)d_in[3];
  const float* b = (const float*)d_in[4];
  float* out = (float*)d_out;

  int n = in_sizes[0] / D;
  int E = in_sizes[1] / 2;
  int step = in_sizes[2] / D;  // = 10
  const int* rows = ei;        // sources
  const int* cols = ei + E;    // targets

  char* p = (char*)d_ws;
  auto alloc = [&](size_t bytes) { char* r = p; p += align_up(bytes, 256); return r; };
  int*   deg     = (int*)alloc((size_t)n * 4);
  float* dinv    = (float*)alloc((size_t)n * 4);
  int*   row_ptr = (int*)alloc((size_t)(n + 1) * 4);
  int*   cursor  = (int*)alloc((size_t)n * 4);
  int*   bsum    = (int*)alloc(2048);
  int2*  csr     = (int2*)alloc((size_t)E * 8);
  float* tn      = (float*)alloc((size_t)step * D * 4);
  uint*  Wpk     = (uint*)alloc((size_t)O * 64 * 4);

  size_t NS = (size_t)n * 64;  // uints per h buffer
  size_t base = (size_t)(p - (char*)d_ws);
  size_t full_need = base + (size_t)(step - 1) * NS * 4;
  bool full = (ws_size >= full_need) && (step >= 3);

  // ---- common setup ----
  hipMemsetAsync(deg, 0, (size_t)n * 4, stream);
  int nb1 = (n + 255) / 256;
  count_deg_k<<<(E + 255) / 256, 256, 0, stream>>>(cols, deg, E, n);
  scan1_k<<<nb1, 256, 0, stream>>>(deg, row_ptr, bsum, dinv, n);
  scan2_k<<<1, 512, 0, stream>>>(bsum, nb1);
  scan3_k<<<nb1, 256, 0, stream>>>(bsum, deg, row_ptr, cursor, n);
  fill_k<<<(E + 255) / 256, 256, 0, stream>>>(rows, cols, cursor, dinv, csr, E, n);
  prep_k<<<1, 256, 0, stream>>>(t, tn, W, Wpk, step);

  int hop_blocks = (n + 3) / 4;  // 1 node/wave, 4 waves/block
  int proj_blocks = 2048;        // high concurrency for the streaming proj
  int nwaves = proj_blocks * 4;

  if (full) {
    uint* hbuf = (uint*)alloc((size_t)(step - 1) * NS * 4);
    // h0 (f16) lives in slot step-2; the final hop overwrites it with h_{step-1}
    uint* h0 = hbuf + (size_t)(step - 2) * NS;
    init_h_k<<<((size_t)NS + 255) / 256, 256, 0, stream>>>(x, h0, (int)NS);
    // hop 1: h0 -> slot 0
    hop_k<false><<<hop_blocks, 256, 0, stream>>>(h0, hbuf, row_ptr, csr, dinv, n);
    for (int k = 2; k < step; ++k) {
      hop_k<false><<<hop_blocks, 256, 0, stream>>>(hbuf + (size_t)(k - 2) * NS,
                                                   hbuf + (size_t)(k - 1) * NS,
                                                   row_ptr, csr, dinv, n);
    }
    if (step == 10)
      proj_k<10><<<proj_blocks, 256, 0, stream>>>(x, hbuf, NS, Wpk, tn, b, out, n, nwaves, step);
    else
      proj_k<0><<<proj_blocks, 256, 0, stream>>>(x, hbuf, NS, Wpk, tn, b, out, n, nwaves, step);
  } else {
    // fallback: ping-pong with fused y (3 buffers)
    uint* h_a  = (uint*)alloc(NS * 4);
    uint* h_b  = (uint*)alloc(NS * 4);
    uint* ybuf = (uint*)alloc(NS * 4);
    init_h_k<<<((size_t)NS + 255) / 256, 256, 0, stream>>>(x, h_a, (int)NS);
    uint* ho = h_a;
    uint* hn = h_b;
    for (int k = 1; k < step; ++k) {
      const float* tp = tn + (size_t)(k - 1) * D;
      const float* tc = tn + (size_t)k * D;
      if (k & 1) {
        if (k == 1)
          hop_f_k<1><<<hop_blocks, 256, 0, stream>>>(ho, hn, ybuf, row_ptr, csr, dinv, tp, tc, n);
        else
          hop_f_k<2><<<hop_blocks, 256, 0, stream>>>(ho, hn, ybuf, row_ptr, csr, dinv, tp, tc, n);
      } else {
        hop_f_k<0><<<hop_blocks, 256, 0, stream>>>(ho, hn, ybuf, row_ptr, csr, dinv, tp, tc, n);
      }
      uint* tmp = ho; ho = hn; hn = tmp;
    }
    proj_y_k<<<512, 256, 0, stream>>>(ybuf, Wpk, b, out, n, 2048);
  }
}

// Round 10
// 517.189 us; speedup vs baseline: 5.2950x; 1.0033x over previous
//
#include <hip/hip_runtime.h>

typedef _Float16 half2_t __attribute__((ext_vector_type(2)));
typedef unsigned int uint;

#define D 128
#define O 64
#define UNR 8

static inline size_t align_up(size_t x, size_t a) { return (x + a - 1) & ~(a - 1); }

__device__ __forceinline__ uint pack_f16(float a, float b) {
  half2_t h;
  h.x = (_Float16)a;
  h.y = (_Float16)b;
  return *(uint*)&h;
}

__device__ __forceinline__ float dot2f(uint a, uint b, float c) {
#if defined(__has_builtin) && __has_builtin(__builtin_amdgcn_fdot2)
  return __builtin_amdgcn_fdot2(*(half2_t*)&a, *(half2_t*)&b, c, false);
#else
  half2_t ha = *(half2_t*)&a, hb = *(half2_t*)&b;
  return c + (float)ha.x * (float)hb.x + (float)ha.y * (float)hb.y;
#endif
}

// ---------------- setup kernels ----------------
// deg = in-edge count (no self loop; memset to 0 before). dinv = rsqrt(deg+1).

__global__ void count_deg_k(const int* __restrict__ col, int* __restrict__ deg, int E, int n) {
  int i = blockIdx.x * blockDim.x + threadIdx.x;
  if (i >= E) return;
  int c = col[i];
  if ((unsigned)c >= (unsigned)n) return;
  atomicAdd(&deg[c], 1);
}

__global__ void scan1_k(const int* __restrict__ deg, int* __restrict__ row_ptr,
                        int* __restrict__ bsum, float* __restrict__ dinv, int n) {
  __shared__ int s[256];
  int tid = threadIdx.x;
  int gid = blockIdx.x * 256 + tid;
  int dg = (gid < n) ? deg[gid] : 0;
  if (gid < n) dinv[gid] = rsqrtf((float)(dg + 1));
  s[tid] = dg;
  __syncthreads();
  for (int off = 1; off < 256; off <<= 1) {
    int t = (tid >= off) ? s[tid - off] : 0;
    __syncthreads();
    s[tid] += t;
    __syncthreads();
  }
  if (gid < n) row_ptr[gid] = s[tid] - dg;  // block-local exclusive
  if (tid == 255) bsum[blockIdx.x] = s[255];
}

__global__ void scan2_k(int* __restrict__ bsum, int nb) {
  __shared__ int s[512];
  int tid = threadIdx.x;
  int v = (tid < nb) ? bsum[tid] : 0;
  s[tid] = v;
  __syncthreads();
  for (int off = 1; off < 512; off <<= 1) {
    int t = (tid >= off) ? s[tid - off] : 0;
    __syncthreads();
    s[tid] += t;
    __syncthreads();
  }
  if (tid < nb) bsum[tid] = s[tid] - v;
}

__global__ void scan3_k(const int* __restrict__ bsum, const int* __restrict__ deg,
                        int* __restrict__ row_ptr, int* __restrict__ cursor, int n) {
  int gid = blockIdx.x * 256 + threadIdx.x;
  if (gid < n) {
    int r = row_ptr[gid] + bsum[blockIdx.x];
    row_ptr[gid] = r;
    cursor[gid] = r;
    if (gid == n - 1) row_ptr[n] = r + deg[gid];
  }
}

__global__ void fill_k(const int* __restrict__ rows, const int* __restrict__ cols,
                       int* __restrict__ cursor, const float* __restrict__ dinv,
                       int2* __restrict__ csr, int E, int n) {
  int i = blockIdx.x * blockDim.x + threadIdx.x;
  if (i >= E) return;
  int u = rows[i], v = cols[i];
  if ((unsigned)v >= (unsigned)n) return;  // must match count_deg_k skip
  if ((unsigned)u >= (unsigned)n) u = 0;
  int slot = atomicAdd(&cursor[v], 1);
  float nrm = dinv[u] * dinv[v];
  csr[slot] = make_int2(u, __float_as_int(nrm));
}

// softmax over hop weights + pack W to f16x2, TRANSPOSED: Wpk[dd*64+o]
__global__ void prep_k(const float* __restrict__ t, float* __restrict__ tn,
                       const float* __restrict__ W, uint* __restrict__ Wpk, int step) {
  int tid = threadIdx.x;
  if (tid < D) {
    float vals[16];
    float m = -1e30f;
    for (int k = 0; k < step; ++k) { vals[k] = t[k * D + tid]; m = fmaxf(m, vals[k]); }
    float ssum = 0.f;
    for (int k = 0; k < step; ++k) { vals[k] = expf(vals[k] - m); ssum += vals[k]; }
    float inv = 1.f / ssum;
    for (int k = 0; k < step; ++k) tn[k * D + tid] = vals[k] * inv;
  }
  for (int i = tid; i < O * 64; i += 256) {
    int o = i & 63, dd = i >> 6;  // i = dd*64 + o
    Wpk[i] = pack_f16(W[o * D + 2 * dd], W[o * D + 2 * dd + 1]);
  }
}

__global__ void init_h_k(const float* __restrict__ x, uint* __restrict__ h0, int total) {
  int i = blockIdx.x * blockDim.x + threadIdx.x;
  if (i >= total) return;
  float2 v = ((const float2*)x)[i];
  h0[i] = pack_f16(v.x, v.y);
}

// ---------------- hop: pure SpMM h_dst = A_norm * h_src ----------------
// One wave per node; 8-wide pipelined 256B f16 gathers (2 lines/edge).

__global__ __launch_bounds__(256) void hop_k(
    const uint* __restrict__ hsrc, uint* __restrict__ hdst,
    const int* __restrict__ row_ptr, const int2* __restrict__ csr,
    const float* __restrict__ dinv, int n) {
  int wid = (blockIdx.x * blockDim.x + threadIdx.x) >> 6;
  int lane = threadIdx.x & 63;
  if (wid >= n) return;
  int v = __builtin_amdgcn_readfirstlane(wid);
  float dv = dinv[v];
  float ns = dv * dv;  // self-loop norm
  uint hp = hsrc[(size_t)v * 64 + lane];
  half2_t hv = *(half2_t*)&hp;
  float hx = (float)hv.x, hy = (float)hv.y;
  float ax = ns * hx, ay = ns * hy;
  int beg = __builtin_amdgcn_readfirstlane(row_ptr[v]);
  int end = __builtin_amdgcn_readfirstlane(row_ptr[v + 1]);
  for (int i = beg; i < end; i += UNR) {
    int u[UNR];
    float w[UNR];
#pragma unroll
    for (int j = 0; j < UNR; ++j) {
      int ic = i + j;
      int icl = (ic < end - 1) ? ic : (end - 1);
      int2 e = csr[icl];
      u[j] = e.x;
      w[j] = (ic < end) ? __int_as_float(e.y) : 0.f;
    }
    uint g[UNR];
#pragma unroll
    for (int j = 0; j < UNR; ++j) g[j] = hsrc[(size_t)u[j] * 64 + lane];
#pragma unroll
    for (int j = 0; j < UNR; ++j) {
      half2_t h = *(half2_t*)&g[j];
      ax += w[j] * (float)h.x;
      ay += w[j] * (float)h.y;
    }
  }
  hdst[(size_t)v * 64 + lane] = pack_f16(ax, ay);
}

// ---------------- proj ----------------
// XF16=true : hbuf slots 0..step-1 hold f16 h_0..h_{step-1}; x unused.
// XF16=false: x is fp32; hbuf slots 0..step-2 hold h_1..h_{step-1}.
// Chunked node ownership: each wave owns PNW contiguous nodes (2KB runs/stream).

#define PNW 8

template <int STEPT, bool XF16>
__global__ __launch_bounds__(256) void proj_k(
    const float* __restrict__ x, const uint* __restrict__ hbuf, size_t hstride,
    const uint* __restrict__ Wpk, const float* __restrict__ tn,
    const float* __restrict__ b, float* __restrict__ out, int n, int step) {
  __shared__ uint sy[4][64];
  int tid = threadIdx.x;
  int lane = tid & 63, wv = tid >> 6;
  uint wreg[64];
#pragma unroll
  for (int j = 0; j < 64; ++j) wreg[j] = Wpk[j * 64 + lane];  // coalesced (transposed)
  float bias = b[lane];
  float2 tt[STEPT > 0 ? STEPT : 1];
  if (STEPT > 0) {
#pragma unroll
    for (int k = 0; k < STEPT; ++k) tt[k] = ((const float2*)(tn + (size_t)k * D))[lane];
  }
  int wid = (blockIdx.x * blockDim.x + tid) >> 6;
  int vb = wid * PNW;
  int ve = vb + PNW < n ? vb + PNW : n;
  for (int v = vb; v < ve; ++v) {
    float yx, yy;
    if (STEPT > 0) {
      if (XF16) {
        uint hp = hbuf[(size_t)v * 64 + lane];
        half2_t h = *(half2_t*)&hp;
        yx = tt[0].x * (float)h.x;
        yy = tt[0].y * (float)h.y;
#pragma unroll
        for (int k = 1; k < STEPT; ++k) {
          uint hq = hbuf[(size_t)k * hstride + (size_t)v * 64 + lane];
          half2_t hh = *(half2_t*)&hq;
          yx += tt[k].x * (float)hh.x;
          yy += tt[k].y * (float)hh.y;
        }
      } else {
        float2 xv = ((const float2*)x)[(size_t)v * 64 + lane];
        yx = tt[0].x * xv.x;
        yy = tt[0].y * xv.y;
#pragma unroll
        for (int k = 1; k < STEPT; ++k) {
          uint hq = hbuf[(size_t)(k - 1) * hstride + (size_t)v * 64 + lane];
          half2_t hh = *(half2_t*)&hq;
          yx += tt[k].x * (float)hh.x;
          yy += tt[k].y * (float)hh.y;
        }
      }
    } else {
      float2 t0 = ((const float2*)tn)[lane];
      float2 xv = ((const float2*)x)[(size_t)v * 64 + lane];
      yx = t0.x * xv.x;
      yy = t0.y * xv.y;
      for (int k = 1; k < step; ++k) {
        uint hq = hbuf[(size_t)(k - 1) * hstride + (size_t)v * 64 + lane];
        half2_t hh = *(half2_t*)&hq;
        float2 tk = ((const float2*)(tn + (size_t)k * D))[lane];
        yx += tk.x * (float)hh.x;
        yy += tk.y * (float)hh.y;
      }
    }
    sy[wv][lane] = pack_f16(yx, yy);  // wave-local broadcast buffer
    float acc = bias;
#pragma unroll
    for (int q = 0; q < 16; ++q) {
      uint4 yq = *(const uint4*)&sy[wv][q * 4];  // broadcast b128 read
      acc = dot2f(yq.x, wreg[q * 4 + 0], acc);
      acc = dot2f(yq.y, wreg[q * 4 + 1], acc);
      acc = dot2f(yq.z, wreg[q * 4 + 2], acc);
      acc = dot2f(yq.w, wreg[q * 4 + 3], acc);
    }
    out[(size_t)v * O + lane] = acc;
  }
}

// ---------------- fallback path (tiny ws): R4-proven structure ----------

template <int DO_Y>
__global__ __launch_bounds__(256) void hop_f_k(
    const uint* __restrict__ h_old, uint* __restrict__ h_new, uint* __restrict__ y,
    const int* __restrict__ row_ptr, const int2* __restrict__ csr,
    const float* __restrict__ dinv, const float* __restrict__ tprev,
    const float* __restrict__ tcur, int n) {
  int wid = (blockIdx.x * blockDim.x + threadIdx.x) >> 6;
  int lane = threadIdx.x & 63;
  if (wid >= n) return;
  int v = __builtin_amdgcn_readfirstlane(wid);
  float dv = dinv[v];
  float ns = dv * dv;
  uint hp = h_old[(size_t)v * 64 + lane];
  half2_t hv = *(half2_t*)&hp;
  float hx = (float)hv.x, hy = (float)hv.y;
  float ax = ns * hx, ay = ns * hy;
  int beg = __builtin_amdgcn_readfirstlane(row_ptr[v]);
  int end = __builtin_amdgcn_readfirstlane(row_ptr[v + 1]);
  for (int i = beg; i < end; i += UNR) {
    int u[UNR];
    float w[UNR];
#pragma unroll
    for (int j = 0; j < UNR; ++j) {
      int ic = i + j;
      int icl = (ic < end - 1) ? ic : (end - 1);
      int2 e = csr[icl];
      u[j] = e.x;
      w[j] = (ic < end) ? __int_as_float(e.y) : 0.f;
    }
    uint g[UNR];
#pragma unroll
    for (int j = 0; j < UNR; ++j) g[j] = h_old[(size_t)u[j] * 64 + lane];
#pragma unroll
    for (int j = 0; j < UNR; ++j) {
      half2_t h = *(half2_t*)&g[j];
      ax += w[j] * (float)h.x;
      ay += w[j] * (float)h.y;
    }
  }
  h_new[(size_t)v * 64 + lane] = pack_f16(ax, ay);
  if (DO_Y) {
    float2 ta = ((const float2*)tprev)[lane];
    float2 tb = ((const float2*)tcur)[lane];
    float yx = ta.x * hx + tb.x * ax;
    float yy = ta.y * hy + tb.y * ay;
    if (DO_Y == 2) {
      uint yo = y[(size_t)v * 64 + lane];
      half2_t yh = *(half2_t*)&yo;
      yx += (float)yh.x;
      yy += (float)yh.y;
    }
    y[(size_t)v * 64 + lane] = pack_f16(yx, yy);
  }
}

__global__ __launch_bounds__(256) void proj_y_k(
    const uint* __restrict__ y, const uint* __restrict__ Wpk,
    const float* __restrict__ b, float* __restrict__ out, int n, int nwaves) {
  int lane = threadIdx.x & 63;
  int wid = (blockIdx.x * blockDim.x + threadIdx.x) >> 6;
  uint wreg[64];
#pragma unroll
  for (int j = 0; j < 64; ++j) wreg[j] = Wpk[j * 64 + lane];  // transposed layout
  float bias = b[lane];
  for (int v = wid; v < n; v += nwaves) {
    int vu = __builtin_amdgcn_readfirstlane(v);
    const uint* yrow = y + (size_t)vu * 64;
    float acc = bias;
#pragma unroll
    for (int dd = 0; dd < 64; ++dd) acc = dot2f(yrow[dd], wreg[dd], acc);
    out[(size_t)vu * O + lane] = acc;
  }
}

// ---------------- launch ----------------

extern "C" void kernel_launch(void* const* d_in, const int* in_sizes, int n_in,
                              void* d_out, int out_size, void* d_ws, size_t ws_size,
                              hipStream_t stream) {
  const float* x = (const float*)d_in[0];
  const int* ei = (const int*)d_in[1];
  const float* t = (const float*)d_in[2];
  const float* W = (const float*)d_in[3];
  const float* b = (const float*)d_in[4];
  float* out = (float*)d_out;

  int n = in_sizes[0] / D;
  int E = in_sizes[1] / 2;
  int step = in_sizes[2] / D;  // = 10
  const int* rows = ei;        // sources
  const int* cols = ei + E;    // targets

  char* p = (char*)d_ws;
  auto alloc = [&](size_t bytes) { char* r = p; p += align_up(bytes, 256); return r; };
  int*   deg     = (int*)alloc((size_t)n * 4);
  float* dinv    = (float*)alloc((size_t)n * 4);
  int*   row_ptr = (int*)alloc((size_t)(n + 1) * 4);
  int*   cursor  = (int*)alloc((size_t)n * 4);
  int*   bsum    = (int*)alloc(2048);
  int2*  csr     = (int2*)alloc((size_t)E * 8);
  float* tn      = (float*)alloc((size_t)step * D * 4);
  uint*  Wpk     = (uint*)alloc((size_t)O * 64 * 4);

  size_t NS = (size_t)n * 64;  // uints per h buffer
  size_t base = (size_t)(p - (char*)d_ws);
  bool fullx = (ws_size >= base + (size_t)step * NS * 4) && (step >= 3);       // 10 slots
  bool full  = (ws_size >= base + (size_t)(step - 1) * NS * 4) && (step >= 3); // 9 slots

  // ---- common setup ----
  hipMemsetAsync(deg, 0, (size_t)n * 4, stream);
  int nb1 = (n + 255) / 256;
  count_deg_k<<<(E + 255) / 256, 256, 0, stream>>>(cols, deg, E, n);
  scan1_k<<<nb1, 256, 0, stream>>>(deg, row_ptr, bsum, dinv, n);
  scan2_k<<<1, 512, 0, stream>>>(bsum, nb1);
  scan3_k<<<nb1, 256, 0, stream>>>(bsum, deg, row_ptr, cursor, n);
  fill_k<<<(E + 255) / 256, 256, 0, stream>>>(rows, cols, cursor, dinv, csr, E, n);
  prep_k<<<1, 256, 0, stream>>>(t, tn, W, Wpk, step);

  int hop_blocks = (n + 3) / 4;  // 1 node/wave, 4 waves/block
  int proj_blocks = (n + PNW * 4 - 1) / (PNW * 4);

  if (fullx) {
    // 10 slots: slot k = h_k (slot 0 = f16(x)); proj reads f16 only
    uint* hbuf = (uint*)alloc((size_t)step * NS * 4);
    init_h_k<<<((size_t)NS + 255) / 256, 256, 0, stream>>>(x, hbuf, (int)NS);
    for (int k = 1; k < step; ++k) {
      hop_k<<<hop_blocks, 256, 0, stream>>>(hbuf + (size_t)(k - 1) * NS,
                                            hbuf + (size_t)k * NS, row_ptr, csr, dinv, n);
    }
    if (step == 10)
      proj_k<10, true><<<proj_blocks, 256, 0, stream>>>(x, hbuf, NS, Wpk, tn, b, out, n, step);
    else
      proj_k<0, false><<<proj_blocks, 256, 0, stream>>>(x, hbuf + NS, NS, Wpk, tn, b, out, n, step);
  } else if (full) {
    // 9 slots: h0 parked in slot step-2, overwritten by the final hop
    uint* hbuf = (uint*)alloc((size_t)(step - 1) * NS * 4);
    uint* h0 = hbuf + (size_t)(step - 2) * NS;
    init_h_k<<<((size_t)NS + 255) / 256, 256, 0, stream>>>(x, h0, (int)NS);
    hop_k<<<hop_blocks, 256, 0, stream>>>(h0, hbuf, row_ptr, csr, dinv, n);
    for (int k = 2; k < step; ++k) {
      hop_k<<<hop_blocks, 256, 0, stream>>>(hbuf + (size_t)(k - 2) * NS,
                                            hbuf + (size_t)(k - 1) * NS, row_ptr, csr, dinv, n);
    }
    if (step == 10)
      proj_k<10, false><<<proj_blocks, 256, 0, stream>>>(x, hbuf, NS, Wpk, tn, b, out, n, step);
    else
      proj_k<0, false><<<proj_blocks, 256, 0, stream>>>(x, hbuf, NS, Wpk, tn, b, out, n, step);
  } else {
    // fallback: ping-pong with fused y (3 buffers)
    uint* h_a  = (uint*)alloc(NS * 4);
    uint* h_b  = (uint*)alloc(NS * 4);
    uint* ybuf = (uint*)alloc(NS * 4);
    init_h_k<<<((size_t)NS + 255) / 256, 256, 0, stream>>>(x, h_a, (int)NS);
    uint* ho = h_a;
    uint* hn = h_b;
    for (int k = 1; k < step; ++k) {
      const float* tp = tn + (size_t)(k - 1) * D;
      const float* tc = tn + (size_t)k * D;
      if (k & 1) {
        if (k == 1)
          hop_f_k<1><<<hop_blocks, 256, 0, stream>>>(ho, hn, ybuf, row_ptr, csr, dinv, tp, tc, n);
        else
          hop_f_k<2><<<hop_blocks, 256, 0, stream>>>(ho, hn, ybuf, row_ptr, csr, dinv, tp, tc, n);
      } else {
        hop_f_k<0><<<hop_blocks, 256, 0, stream>>>(ho, hn, ybuf, row_ptr, csr, dinv, tp, tc, n);
      }
      uint* tmp = ho; ho = hn; hn = tmp;
    }
    proj_y_k<<<512, 256, 0, stream>>>(ybuf, Wpk, b, out, n, 2048);
  }
}